// Round 4
// baseline (683.153 us; speedup 1.0000x reference)
//
#include <hip/hip_runtime.h>

// Morphological skeleton, 16 x 1024 x 1024 f32.
// skel = sum_{k=0..20} ( e_k - dilate3x3(e_{k+1}) ),  e_0 = x, e_{k+1} = erode3x3(e_k)
// (reduce_window SAME semantics: windows clamp at image borders).
//
// Register-resident vertical pipeline, zero LDS tile. 3 dispatches x G=7 fused
// erosion stages. One wave (64 lanes x float4) owns a 256-col band; each wave
// now runs TWO independent row-chunk sweeps (y0, y0+32) interleaved.
//
// Round-8 change vs round 7 (361 us): ILP, not occupancy. Evidence across
// rounds: 2x waves -> flat time; 4-wave workgroups -> flat time; +35% VALU ->
// +38% time; occupancy pinned ~14.6% (~1.2 waves/SIMD resident) regardless of
// launch shape. Model: residency is HW-capped, each wave is one long
// dependent chain (min3 -> bpermute -> min3 -> max3 -> bpermute per stage),
// so issue duty is stuck at 40-49%. Fix: dual-sweep waves — two complete,
// independent pipeline states (A: y0, B: y0+32) interleaved in the same basic
// block, letting the compile-time scheduler fill chain-A stalls with chain-B
// work. Wave count back to 1280 (48 steps, 2x work/step). Inner step body is
// byte-identical to round 7's proven formulation.
//
// Correctness invariants (desk-verified):
//  - sweeps A/B touch disjoint row ranges of the same band; writes disjoint.
//  - y0a = 64j, y0b = 64j+32: both t0 = y0-8 even -> parity mapping of
//    pf/skpf slots holds for both sweeps.
//  - EDGE folding per sub-sweep: interior iff 32 <= y0 <= 960 (proof: topOK
//    min at y0-17 >= 0 iff y0 >= 32; botOK max at y0+38 < 1024 iff y0 <= 960).
//    Pair j=0: A(y0=0) edge, B(32) interior; j=15: A(960) interior, B(992)
//    edge; others interior/interior.
//  - synthetic erode values at OOB/warm-up rows are >= the true clamped
//    erosion => harmless in min chains; masked to -BIG in dilate maxes via
//    wave-uniform row conditionals (EDGE path only).
//  - halos exactly tight: 8 rows warm-up (t0 = y0-8), 8 cols/side shrink;
//    bands own disjoint column ranges {[0,248),[248,488),[488,728),[728,968),
//    [968,1024)} so the skel read-modify-write never races.

static constexpr int W = 1024, H = 1024, NIMG = 16;
static constexpr int RCH = 32;           // output rows per sweep
static constexpr int NSTEP = RCH + 16;   // sweep steps (8 warm-up + 8 drain)
static constexpr float BIG = 3.0e38f;

__device__ __forceinline__ float min3f(float a, float b, float c) { return fminf(fminf(a, b), c); }
__device__ __forceinline__ float max3f(float a, float b, float c) { return fmaxf(fmaxf(a, b), c); }

template<bool FIRST, bool WRITE_E, bool EDGE, int PFI>
__device__ __forceinline__
void pipe_step(int t, int y0, int lane, int gx,
               bool leftEdge, bool rightEdge, bool lane_ok,
               const float* __restrict__ in, float* __restrict__ eo,
               float* __restrict__ sk,
               float4 (&OB)[7], float4 (&MB)[7], float4& OD, float4& MD,
               float4 (&acc)[8], float4 (&pf)[2], float4 (&skpf)[2])
{
    // consume input row t (OOB rows are +BIG: erode identity; interior: always in-image)
    float4 cur;
    if (!EDGE || (unsigned)t < (unsigned)H) cur = pf[PFI];
    else                                    cur = make_float4(BIG, BIG, BIG, BIG);
    // prefetch input row t+2 into the slot just consumed
    {
        const int nr = t + 2;
        if ((!EDGE || (unsigned)nr < (unsigned)H) && nr <= y0 + RCH + 7)
            pf[PFI] = *(const float4*)&in[(size_t)nr * W + gx];
    }

#pragma unroll
    for (int s = 0; s < 7; ++s) {
        // invariant at entry: OB[s] = f_s(t-s-2), MB[s] = f_s(t-s-1),
        // cur = f_s(t-s) (produced this step by the previous stage / load).
        const float4 fOld = OB[s];
        const float4 fMid = MB[s];

        // ---- erode: en = f_{s+1}(t-s-1) ----
        float4 vm;
        vm.x = min3f(fOld.x, fMid.x, cur.x);
        vm.y = min3f(fOld.y, fMid.y, cur.y);
        vm.z = min3f(fOld.z, fMid.z, cur.z);
        vm.w = min3f(fOld.w, fMid.w, cur.w);
        float lft = __shfl(vm.w, lane - 1);   // lane 0: garbage -> invalid cols
        float rgt = __shfl(vm.x, lane + 1);   // lane 63: garbage -> invalid cols
        if (leftEdge)  lft = BIG;             // true image border clamp
        if (rightEdge) rgt = BIG;
        float4 en;
        en.x = min3f(lft,  vm.x, vm.y);
        en.y = min3f(vm.x, vm.y, vm.z);
        en.z = min3f(vm.y, vm.z, vm.w);
        en.w = min3f(vm.z, vm.w, rgt);

        OB[s] = cur;   // old-role slot receives newest f_s row (parity swap)

        // ---- dilate of f_{s+1} centered at row t-s-2 ----
        // gOld/gMid from stage s+1's buffers, read BEFORE their update in
        // iteration s+1 of this same step.
        float4 gOld, gMid;
        if (s < 6) { gOld = OB[s + 1]; gMid = MB[s + 1]; }  // f_{s+1}(t-s-3), (t-s-2)
        else       { gOld = OD;        gMid = MD;        }
        const bool topOK = !EDGE || ((t - s - 3) >= 0);   // row t-s-3 in-image?
        const bool botOK = !EDGE || ((t - s - 1) < H);    // row t-s-1 in-image?
        float4 vx;
        {
            float txx = topOK ? gOld.x : -BIG, bxx = botOK ? en.x : -BIG;
            float txy = topOK ? gOld.y : -BIG, bxy = botOK ? en.y : -BIG;
            float txz = topOK ? gOld.z : -BIG, bxz = botOK ? en.z : -BIG;
            float txw = topOK ? gOld.w : -BIG, bxw = botOK ? en.w : -BIG;
            vx.x = max3f(txx, gMid.x, bxx);
            vx.y = max3f(txy, gMid.y, bxy);
            vx.z = max3f(txz, gMid.z, bxz);
            vx.w = max3f(txw, gMid.w, bxw);
        }
        float dl = __shfl(vx.w, lane - 1);
        float dr = __shfl(vx.x, lane + 1);
        if (leftEdge)  dl = -BIG;
        if (rightEdge) dr = -BIG;
        float4 dn;
        dn.x = max3f(dl,   vx.x, vx.y);
        dn.y = max3f(vx.x, vx.y, vx.z);
        dn.z = max3f(vx.y, vx.z, vx.w);
        dn.w = max3f(vx.z, vx.w, dr);

        // term_s(t-s-2) = f_s(t-s-2) - dilate(f_{s+1})(t-s-2); FIFO slot 6-s
        acc[6 - s].x += fOld.x - dn.x;
        acc[6 - s].y += fOld.y - dn.y;
        acc[6 - s].z += fOld.z - dn.z;
        acc[6 - s].w += fOld.w - dn.w;

        if (s == 6) {
            if (WRITE_E) {
                const int er = t - 7;          // en = f_7(t-7)
                if (er >= y0 && er < y0 + RCH && lane_ok)
                    *(float4*)&eo[(size_t)er * W + gx] = en;
            }
            OD = en;
        }
        cur = en;   // becomes f_{s+1}(t-(s+1)) for the next stage
    }

    // ---- emit completed row t-8 ----
    if (t >= y0 + 8) {
        const int r = t - 8;
        float4 v = acc[0];
        if (!FIRST) {
            const float4 o = skpf[PFI];        // skel row t-8, prefetched at step t-2
            v.x += o.x; v.y += o.y; v.z += o.z; v.w += o.w;
        }
        if (lane_ok)
            *(float4*)&sk[(size_t)r * W + gx] = v;
    }
#pragma unroll
    for (int j = 0; j < 7; ++j) acc[j] = acc[j + 1];
    acc[7] = make_float4(0.f, 0.f, 0.f, 0.f);

    // ---- prefetch old skel row t-6 AFTER emission (consumed at step t+2,
    //      which shares this step's parity and thus this PFI slot) ----
    if (!FIRST) {
        const int pr = t - 6;
        if (pr >= y0 && pr < y0 + RCH)
            skpf[PFI] = *(const float4*)&sk[(size_t)pr * W + gx];
    }
}

template<bool FIRST, bool WRITE_E, bool EA, bool EB>
__device__ __forceinline__
void sweep2(int y0a, int y0b, int lane, int gx,
            bool leftEdge, bool rightEdge, bool lane_ok,
            const float* __restrict__ in, float* __restrict__ eo,
            float* __restrict__ sk)
{
    const float4 big4 = make_float4(BIG, BIG, BIG, BIG);
    const float4 z4   = make_float4(0.f, 0.f, 0.f, 0.f);

    // sweep A state
    float4 A_B0[7], A_B1[7], A_D0, A_D1, A_acc[8], A_pf[2], A_skpf[2];
    // sweep B state
    float4 B_B0[7], B_B1[7], B_D0, B_D1, B_acc[8], B_pf[2], B_skpf[2];

#pragma unroll
    for (int s = 0; s < 7; ++s) {
        A_B0[s] = big4; A_B1[s] = big4;
        B_B0[s] = big4; B_B1[s] = big4;
    }
    A_D0 = big4; A_D1 = big4; B_D0 = big4; B_D1 = big4;
#pragma unroll
    for (int j = 0; j < 8; ++j) { A_acc[j] = z4; B_acc[j] = z4; }
    A_pf[0] = big4; A_pf[1] = big4; A_skpf[0] = z4; A_skpf[1] = z4;
    B_pf[0] = big4; B_pf[1] = big4; B_skpf[0] = z4; B_skpf[1] = z4;

    // prefetch input rows t0, t0+1 for both sweeps (interior: always in-image)
    {
        const int a0 = y0a - 8, a1 = y0a - 7;
        if (!EA || a0 >= 0) A_pf[0] = *(const float4*)&in[(size_t)a0 * W + gx];
        if (!EA || a1 >= 0) A_pf[1] = *(const float4*)&in[(size_t)a1 * W + gx];
        const int b0 = y0b - 8, b1 = y0b - 7;
        if (!EB || b0 >= 0) B_pf[0] = *(const float4*)&in[(size_t)b0 * W + gx];
        if (!EB || b1 >= 0) B_pf[1] = *(const float4*)&in[(size_t)b1 * W + gx];
    }

    int ta = y0a - 8;   // even (y0a = 64j) -> parity mapping holds
    int tb = y0b - 8;   // even (y0b = 64j+32)
#pragma unroll 1
    for (int i = 0; i < NSTEP; i += 2) {
        // interleaved: the scheduler fills chain-A stalls with chain-B work
        pipe_step<FIRST, WRITE_E, EA, 0>(ta,     y0a, lane, gx, leftEdge, rightEdge, lane_ok,
                                         in, eo, sk, A_B0, A_B1, A_D0, A_D1, A_acc, A_pf, A_skpf);
        pipe_step<FIRST, WRITE_E, EB, 0>(tb,     y0b, lane, gx, leftEdge, rightEdge, lane_ok,
                                         in, eo, sk, B_B0, B_B1, B_D0, B_D1, B_acc, B_pf, B_skpf);
        pipe_step<FIRST, WRITE_E, EA, 1>(ta + 1, y0a, lane, gx, leftEdge, rightEdge, lane_ok,
                                         in, eo, sk, A_B1, A_B0, A_D1, A_D0, A_acc, A_pf, A_skpf);
        pipe_step<FIRST, WRITE_E, EB, 1>(tb + 1, y0b, lane, gx, leftEdge, rightEdge, lane_ok,
                                         in, eo, sk, B_B1, B_B0, B_D1, B_D0, B_acc, B_pf, B_skpf);
        ta += 2; tb += 2;
    }
}

template<bool FIRST, bool WRITE_E>
__global__ __launch_bounds__(64)
void skel_pipe(const float* __restrict__ ein, float* __restrict__ eout,
               float* __restrict__ skel)
{
    const int lane = threadIdx.x;          // one wave per block
    const int bx = blockIdx.x;             // band 0..4
    const int pr = blockIdx.y;             // row-chunk pair 0..15
    const int img = blockIdx.z;
    const int y0a = pr * (2 * RCH);        // 64j
    const int y0b = y0a + RCH;             // 64j + 32
    const int x0 = (bx == 4) ? 768 : bx * 240;   // last band starts at 1024-256
    const int gx = x0 + 4 * lane;                // gx max = 768 + 252 = 1020

    const size_t base = (size_t)img * (size_t)(W * H);
    const float* __restrict__ in = ein + base;
    float* __restrict__ eo = eout + base;
    float* __restrict__ sk = skel + base;

    const bool leftEdge  = (gx == 0);
    const bool rightEdge = (gx + 4 == W);
    // disjoint write ownership (bands overlap in compute, never in writes)
    const int own_lo = (bx == 0) ? 0 : ((bx == 4) ? 968 : x0 + 8);
    const int own_hi = (bx == 4) ? W : x0 + 248;
    const bool lane_ok = (gx >= own_lo) && (gx < own_hi);

    // interior iff 32 <= y0 <= 960 (header proof); pairs are (64j, 64j+32)
    if (pr == 0)
        sweep2<FIRST, WRITE_E, true,  false>(y0a, y0b, lane, gx, leftEdge, rightEdge, lane_ok, in, eo, sk);
    else if (pr == (H / (2 * RCH)) - 1)
        sweep2<FIRST, WRITE_E, false, true >(y0a, y0b, lane, gx, leftEdge, rightEdge, lane_ok, in, eo, sk);
    else
        sweep2<FIRST, WRITE_E, false, false>(y0a, y0b, lane, gx, leftEdge, rightEdge, lane_ok, in, eo, sk);
}

extern "C" void kernel_launch(void* const* d_in, const int* in_sizes, int n_in,
                              void* d_out, int out_size, void* d_ws, size_t ws_size,
                              hipStream_t stream)
{
    const float* x = (const float*)d_in[0];
    float* skel = (float*)d_out;
    const size_t n = (size_t)NIMG * W * H;

    float* e0 = (float*)d_ws;
    float* e1 = e0 + n;

    dim3 grid(5, H / (2 * RCH), NIMG);
    dim3 block(64);

    // steps 0-6: x -> e0 ; 7-13: e0 -> e1 ; 14-20: e1 -> (none)
    skel_pipe<true,  true ><<<grid, block, 0, stream>>>(x,  e0, skel);
    skel_pipe<false, true ><<<grid, block, 0, stream>>>(e0, e1, skel);
    skel_pipe<false, false><<<grid, block, 0, stream>>>(e1, e0, skel);
}

// Round 5
// 324.080 us; speedup vs baseline: 2.1080x; 2.1080x over previous
//
#include <hip/hip_runtime.h>

// Morphological skeleton, 16 x 1024 x 1024 f32.
// skel = sum_{k=0..20} ( e_k - dilate3x3(e_{k+1}) ),  e_0 = x, e_{k+1} = erode3x3(e_k)
// (reduce_window SAME semantics: windows clamp at image borders).
//
// Register-resident vertical pipeline, zero LDS tile. 3 dispatches x G=7 fused
// erosion stages. One wave (64 lanes x float4) owns a 256-col band and sweeps
// RCH+16 rows. Per stage: 2-row register buffer (parity-swapped); erode =
// min3 vertical + lane+-1 horizontal; dilate of f_{s+1} reuses stage s+1's
// buffers; terms go into an 8-deep register FIFO, emitted as rows complete.
//
// Round-9 change vs round 7/8: replace ALL ds_bpermute shuffles with DPP
// whole-wave shifts. Evidence: chip VALU issue rate pinned at ~0.43M instr/us
// (~40% duty) across every occupancy/ILP configuration (R0-R4); time tracks
// VALU count; dual-state ILP and wave count do nothing. => per-wave dependent
// chain bound, dominated by 14 serialized ds_bpermute round-trips (~30-40 cy
// each) per step. CDNA4 (gfx9 lineage) retains DPP wave_shr:1 / wave_shl:1:
// v_mov_b32_dpp is a ~2-cycle VALU op replacing each __shfl(v, lane+-1) 1:1
// -- deletes ~500 cycles of DS latency per step from the critical path at
// zero DS ops remaining.
//  - wave_shr:1 (0x138): lane i <- lane i-1  == old __shfl(v, lane-1)
//  - wave_shl:1 (0x130): lane i <- lane i+1  == old __shfl(v, lane+1)
//  - bound lanes (0 / 63) get 0-fill: lands only in leftEdge/rightEdge-masked
//    lanes or unowned halo columns (contamination <= 1 col/stage, absorbed by
//    the 8-col shrink exactly as the old undefined-shfl garbage was).
//
// Config: round-7's proven best (4-wave WGs, RCH=32, EDGE folding).
//
// Correctness invariants (desk-verified):
//  - interior test: topOK min at y0-17 >= 0 iff y0>=32; botOK max at y0+38 <
//    1024 iff y0<=960. EDGE=true path behaves identically to round 5 for the
//    2 boundary chunks.
//  - y0 = 32k keeps t0 = y0-8 even -> parity mapping of pf/skpf slots holds.
//  - synthetic erode values at OOB/warm-up rows are >= the true clamped
//    erosion => harmless in min chains; masked to -BIG in dilate maxes via
//    wave-uniform row conditionals (EDGE path).
//  - halos exactly tight: 8 rows warm-up (t0 = y0-8), 8 cols/side shrink;
//    bands own disjoint column ranges {[0,248),[248,488),[488,728),[728,968),
//    [968,1024)} so the skel read-modify-write never races.

static constexpr int W = 1024, H = 1024, NIMG = 16;
static constexpr int RCH = 32;           // output rows per wave
static constexpr int NSTEP = RCH + 16;   // sweep steps (8 warm-up + 8 drain)
static constexpr int WPB = 4;            // waves per workgroup
static constexpr float BIG = 3.0e38f;

__device__ __forceinline__ float min3f(float a, float b, float c) { return fminf(fminf(a, b), c); }
__device__ __forceinline__ float max3f(float a, float b, float c) { return fmaxf(fmaxf(a, b), c); }

// DPP whole-wave shifts (gfx9/CDNA-only modes; VALU pipe, no DS).
// wave_shr:1 = 0x138 -> lane i reads lane i-1 (left neighbor); lane 0 = 0.
// wave_shl:1 = 0x130 -> lane i reads lane i+1 (right neighbor); lane 63 = 0.
__device__ __forceinline__ float dpp_left(float v) {
    return __int_as_float(__builtin_amdgcn_mov_dpp(__float_as_int(v), 0x138, 0xF, 0xF, true));
}
__device__ __forceinline__ float dpp_right(float v) {
    return __int_as_float(__builtin_amdgcn_mov_dpp(__float_as_int(v), 0x130, 0xF, 0xF, true));
}

template<bool FIRST, bool WRITE_E, bool EDGE, int PFI>
__device__ __forceinline__
void pipe_step(int t, int y0, int gx,
               bool leftEdge, bool rightEdge, bool lane_ok,
               const float* __restrict__ in, float* __restrict__ eo,
               float* __restrict__ sk,
               float4 (&OB)[7], float4 (&MB)[7], float4& OD, float4& MD,
               float4 (&acc)[8], float4 (&pf)[2], float4 (&skpf)[2])
{
    // consume input row t (OOB rows are +BIG: erode identity; interior: always in-image)
    float4 cur;
    if (!EDGE || (unsigned)t < (unsigned)H) cur = pf[PFI];
    else                                    cur = make_float4(BIG, BIG, BIG, BIG);
    // prefetch input row t+2 into the slot just consumed
    {
        const int nr = t + 2;
        if ((!EDGE || (unsigned)nr < (unsigned)H) && nr <= y0 + RCH + 7)
            pf[PFI] = *(const float4*)&in[(size_t)nr * W + gx];
    }

#pragma unroll
    for (int s = 0; s < 7; ++s) {
        // invariant at entry: OB[s] = f_s(t-s-2), MB[s] = f_s(t-s-1),
        // cur = f_s(t-s) (produced this step by the previous stage / load).
        const float4 fOld = OB[s];
        const float4 fMid = MB[s];

        // ---- erode: en = f_{s+1}(t-s-1) ----
        float4 vm;
        vm.x = min3f(fOld.x, fMid.x, cur.x);
        vm.y = min3f(fOld.y, fMid.y, cur.y);
        vm.z = min3f(fOld.z, fMid.z, cur.z);
        vm.w = min3f(fOld.w, fMid.w, cur.w);
        float lft = dpp_left(vm.w);           // lane 0: 0-fill -> invalid col
        float rgt = dpp_right(vm.x);          // lane 63: 0-fill -> invalid col
        if (leftEdge)  lft = BIG;             // true image border clamp
        if (rightEdge) rgt = BIG;
        float4 en;
        en.x = min3f(lft,  vm.x, vm.y);
        en.y = min3f(vm.x, vm.y, vm.z);
        en.z = min3f(vm.y, vm.z, vm.w);
        en.w = min3f(vm.z, vm.w, rgt);

        OB[s] = cur;   // old-role slot receives newest f_s row (parity swap)

        // ---- dilate of f_{s+1} centered at row t-s-2 ----
        // gOld/gMid from stage s+1's buffers, read BEFORE their update in
        // iteration s+1 of this same step.
        float4 gOld, gMid;
        if (s < 6) { gOld = OB[s + 1]; gMid = MB[s + 1]; }  // f_{s+1}(t-s-3), (t-s-2)
        else       { gOld = OD;        gMid = MD;        }
        const bool topOK = !EDGE || ((t - s - 3) >= 0);   // row t-s-3 in-image?
        const bool botOK = !EDGE || ((t - s - 1) < H);    // row t-s-1 in-image?
        float4 vx;
        {
            float txx = topOK ? gOld.x : -BIG, bxx = botOK ? en.x : -BIG;
            float txy = topOK ? gOld.y : -BIG, bxy = botOK ? en.y : -BIG;
            float txz = topOK ? gOld.z : -BIG, bxz = botOK ? en.z : -BIG;
            float txw = topOK ? gOld.w : -BIG, bxw = botOK ? en.w : -BIG;
            vx.x = max3f(txx, gMid.x, bxx);
            vx.y = max3f(txy, gMid.y, bxy);
            vx.z = max3f(txz, gMid.z, bxz);
            vx.w = max3f(txw, gMid.w, bxw);
        }
        float dl = dpp_left(vx.w);
        float dr = dpp_right(vx.x);
        if (leftEdge)  dl = -BIG;
        if (rightEdge) dr = -BIG;
        float4 dn;
        dn.x = max3f(dl,   vx.x, vx.y);
        dn.y = max3f(vx.x, vx.y, vx.z);
        dn.z = max3f(vx.y, vx.z, vx.w);
        dn.w = max3f(vx.z, vx.w, dr);

        // term_s(t-s-2) = f_s(t-s-2) - dilate(f_{s+1})(t-s-2); FIFO slot 6-s
        acc[6 - s].x += fOld.x - dn.x;
        acc[6 - s].y += fOld.y - dn.y;
        acc[6 - s].z += fOld.z - dn.z;
        acc[6 - s].w += fOld.w - dn.w;

        if (s == 6) {
            if (WRITE_E) {
                const int er = t - 7;          // en = f_7(t-7)
                if (er >= y0 && er < y0 + RCH && lane_ok)
                    *(float4*)&eo[(size_t)er * W + gx] = en;
            }
            OD = en;
        }
        cur = en;   // becomes f_{s+1}(t-(s+1)) for the next stage
    }

    // ---- emit completed row t-8 ----
    if (t >= y0 + 8) {
        const int r = t - 8;
        float4 v = acc[0];
        if (!FIRST) {
            const float4 o = skpf[PFI];        // skel row t-8, prefetched at step t-2
            v.x += o.x; v.y += o.y; v.z += o.z; v.w += o.w;
        }
        if (lane_ok)
            *(float4*)&sk[(size_t)r * W + gx] = v;
    }
#pragma unroll
    for (int j = 0; j < 7; ++j) acc[j] = acc[j + 1];
    acc[7] = make_float4(0.f, 0.f, 0.f, 0.f);

    // ---- prefetch old skel row t-6 AFTER emission (consumed at step t+2,
    //      which shares this step's parity and thus this PFI slot) ----
    if (!FIRST) {
        const int pr = t - 6;
        if (pr >= y0 && pr < y0 + RCH)
            skpf[PFI] = *(const float4*)&sk[(size_t)pr * W + gx];
    }
}

template<bool FIRST, bool WRITE_E, bool EDGE>
__device__ __forceinline__
void sweep(int y0, int gx,
           bool leftEdge, bool rightEdge, bool lane_ok,
           const float* __restrict__ in, float* __restrict__ eo,
           float* __restrict__ sk)
{
    float4 B0[7], B1[7], D0, D1, acc[8], pf[2], skpf[2];
    const float4 big4 = make_float4(BIG, BIG, BIG, BIG);
    const float4 z4   = make_float4(0.f, 0.f, 0.f, 0.f);
#pragma unroll
    for (int s = 0; s < 7; ++s) { B0[s] = big4; B1[s] = big4; }
    D0 = big4; D1 = big4;
#pragma unroll
    for (int j = 0; j < 8; ++j) acc[j] = z4;
    pf[0] = big4; pf[1] = big4; skpf[0] = z4; skpf[1] = z4;

    // prefetch input rows t0, t0+1 (interior: always in-image)
    {
        const int r0 = y0 - 8, r1 = y0 - 7;
        if (!EDGE || r0 >= 0) pf[0] = *(const float4*)&in[(size_t)r0 * W + gx];
        if (!EDGE || r1 >= 0) pf[1] = *(const float4*)&in[(size_t)r1 * W + gx];
    }

    const int t0 = y0 - 8;   // even (y0 multiple of 32) -> parity mapping holds
#pragma unroll 1
    for (int t = t0; t < t0 + NSTEP; t += 2) {
        pipe_step<FIRST, WRITE_E, EDGE, 0>(t,     y0, gx, leftEdge, rightEdge, lane_ok,
                                           in, eo, sk, B0, B1, D0, D1, acc, pf, skpf);
        pipe_step<FIRST, WRITE_E, EDGE, 1>(t + 1, y0, gx, leftEdge, rightEdge, lane_ok,
                                           in, eo, sk, B1, B0, D1, D0, acc, pf, skpf);
    }
}

template<bool FIRST, bool WRITE_E>
__global__ __launch_bounds__(WPB * 64)
void skel_pipe(const float* __restrict__ ein, float* __restrict__ eout,
               float* __restrict__ skel)
{
    const int lane = threadIdx.x;          // 64 lanes; threadIdx.y selects the wave
    const int bx = blockIdx.x;             // band 0..4
    const int y0 = (blockIdx.y * WPB + (int)threadIdx.y) * RCH;  // private row chunk
    const int img = blockIdx.z;
    const int x0 = (bx == 4) ? 768 : bx * 240;   // last band starts at 1024-256
    const int gx = x0 + 4 * lane;                // gx max = 768 + 252 = 1020

    const size_t base = (size_t)img * (size_t)(W * H);
    const float* __restrict__ in = ein + base;
    float* __restrict__ eo = eout + base;
    float* __restrict__ sk = skel + base;

    const bool leftEdge  = (gx == 0);
    const bool rightEdge = (gx + 4 == W);
    // disjoint write ownership (bands overlap in compute, never in writes)
    const int own_lo = (bx == 0) ? 0 : ((bx == 4) ? 968 : x0 + 8);
    const int own_hi = (bx == 4) ? W : x0 + 248;
    const bool lane_ok = (gx >= own_lo) && (gx < own_hi);

    // interior: all topOK/botOK masks constant-true (see header proof)
    if (y0 >= 32 && y0 <= H - RCH - 32)
        sweep<FIRST, WRITE_E, false>(y0, gx, leftEdge, rightEdge, lane_ok, in, eo, sk);
    else
        sweep<FIRST, WRITE_E, true >(y0, gx, leftEdge, rightEdge, lane_ok, in, eo, sk);
}

extern "C" void kernel_launch(void* const* d_in, const int* in_sizes, int n_in,
                              void* d_out, int out_size, void* d_ws, size_t ws_size,
                              hipStream_t stream)
{
    const float* x = (const float*)d_in[0];
    float* skel = (float*)d_out;
    const size_t n = (size_t)NIMG * W * H;

    float* e0 = (float*)d_ws;
    float* e1 = e0 + n;

    dim3 grid(5, H / (RCH * WPB), NIMG);
    dim3 block(64, WPB);

    // steps 0-6: x -> e0 ; 7-13: e0 -> e1 ; 14-20: e1 -> (none)
    skel_pipe<true,  true ><<<grid, block, 0, stream>>>(x,  e0, skel);
    skel_pipe<false, true ><<<grid, block, 0, stream>>>(e0, e1, skel);
    skel_pipe<false, false><<<grid, block, 0, stream>>>(e1, e0, skel);
}